// Round 2
// baseline (438.506 us; speedup 1.0000x reference)
//
#include <hip/hip_runtime.h>
#include <math.h>

#define SQ_ 2048
#define SK_ 2048
#define D_  128
#define SCALE 20.0f

typedef __attribute__((ext_vector_type(8))) __bf16 bf16x8;
typedef __attribute__((ext_vector_type(4))) __bf16 bf16x4;
typedef __attribute__((ext_vector_type(2))) __bf16 bf16x2;
typedef __attribute__((ext_vector_type(4))) float  floatx4;

#define KSTR 136   // K LDS row stride (128 + 8 pad), bytes=272 (16B-aligned rows)
#define VSTR 40    // Vt LDS row stride (32 keys + 8 pad), bytes=80
#define PSTR 40

__global__ __launch_bounds__(256, 2)
void fattn_kernel(const float* __restrict__ Q, const float* __restrict__ K,
                  const float* __restrict__ V, const int* __restrict__ mask,
                  float* __restrict__ Out)
{
    __shared__ __align__(16) __bf16 sKhi[32 * KSTR];
    __shared__ __align__(16) __bf16 sKlo[32 * KSTR];
    __shared__ __align__(16) __bf16 sVt[128 * VSTR];
    __shared__ __align__(16) __bf16 sP[4 * 16 * PSTR];

    const int tid  = threadIdx.x;
    const int w    = tid >> 6;          // wave id 0..3
    const int lane = tid & 63;
    const int m    = lane & 15;
    const int quad = lane >> 4;
    const int qt   = blockIdx.x;        // q-tile (64 rows)
    const int bh   = blockIdx.y;        // fused batch*head

    // ---- load Q A-fragments (hi/lo split, scale folded in) ----
    bf16x8 qhi[4], qlo[4];
    {
        const int qrow = qt * 64 + w * 16 + m;
        const float* qp = Q + ((size_t)(bh * SQ_ + qrow)) * D_;
#pragma unroll
        for (int c = 0; c < 4; ++c) {
            const int d0 = c * 32 + quad * 8;
            floatx4 a = *(const floatx4*)(qp + d0);
            floatx4 b = *(const floatx4*)(qp + d0 + 4);
#pragma unroll
            for (int j = 0; j < 4; ++j) {
                float x = a[j] * SCALE;
                __bf16 h = (__bf16)x;
                qhi[c][j] = h;
                qlo[c][j] = (__bf16)(x - (float)h);
            }
#pragma unroll
            for (int j = 0; j < 4; ++j) {
                float x = b[j] * SCALE;
                __bf16 h = (__bf16)x;
                qhi[c][4 + j] = h;
                qlo[c][4 + j] = (__bf16)(x - (float)h);
            }
        }
    }

    floatx4 O[8];
#pragma unroll
    for (int t = 0; t < 8; ++t) O[t] = (floatx4){0.f, 0.f, 0.f, 0.f};
    float m_i[4] = {-INFINITY, -INFINITY, -INFINITY, -INFINITY};
    float l_i[4] = {0.f, 0.f, 0.f, 0.f};

    const float* Kbh = K + (size_t)bh * SK_ * D_;
    const float* Vbh = V + (size_t)bh * SK_ * D_;
    __bf16* sPw = sP + w * 16 * PSTR;

    for (int kt = 0; kt < SK_ / 32; ++kt) {
        const int kbase = kt * 32;

        // ---- stage K tile (32x128) as hi/lo bf16, row-major ----
#pragma unroll
        for (int i = 0; i < 4; ++i) {
            const int lin = i * 1024 + tid * 4;
            const int key = lin >> 7;
            const int d   = lin & 127;
            floatx4 v = *(const floatx4*)(Kbh + (kbase + key) * D_ + d);
            bf16x4 h4, l4;
#pragma unroll
            for (int j = 0; j < 4; ++j) {
                __bf16 h = (__bf16)v[j];
                h4[j] = h;
                l4[j] = (__bf16)(v[j] - (float)h);
            }
            *(bf16x4*)&sKhi[key * KSTR + d] = h4;
            *(bf16x4*)&sKlo[key * KSTR + d] = l4;
        }
        // ---- stage V tile transposed: sVt[d][key], bf16 ----
#pragma unroll
        for (int i = 0; i < 2; ++i) {
            const int pi   = i * 256 + tid;
            const int kp   = (pi & 15) * 2;       // key pair base
            const int dblk = (pi >> 4);           // 0..31
            const int d0   = dblk * 4;
            floatx4 v0 = *(const floatx4*)(Vbh + (kbase + kp) * D_ + d0);
            floatx4 v1 = *(const floatx4*)(Vbh + (kbase + kp + 1) * D_ + d0);
#pragma unroll
            for (int j = 0; j < 4; ++j) {
                bf16x2 p2;
                p2[0] = (__bf16)v0[j];
                p2[1] = (__bf16)v1[j];
                *(bf16x2*)&sVt[(d0 + j) * VSTR + kp] = p2;
            }
        }
        __syncthreads();

        // ---- S = (20*Q)·K^T : 16 q-rows x 32 keys, split-precision ----
        floatx4 Sv[2];
#pragma unroll
        for (int nt = 0; nt < 2; ++nt) {
            floatx4 acc = (floatx4){0.f, 0.f, 0.f, 0.f};
#pragma unroll
            for (int c = 0; c < 4; ++c) {
                const int off = (nt * 16 + m) * KSTR + c * 32 + quad * 8;
                bf16x8 kh = *(const bf16x8*)&sKhi[off];
                bf16x8 kl = *(const bf16x8*)&sKlo[off];
                acc = __builtin_amdgcn_mfma_f32_16x16x32_bf16(qhi[c], kh, acc, 0, 0, 0);
                acc = __builtin_amdgcn_mfma_f32_16x16x32_bf16(qlo[c], kh, acc, 0, 0, 0);
                acc = __builtin_amdgcn_mfma_f32_16x16x32_bf16(qhi[c], kl, acc, 0, 0, 0);
            }
            Sv[nt] = acc;
        }

        // ---- online softmax; row r lives in this quad's 16 lanes ----
        float alpha[4];
#pragma unroll
        for (int r = 0; r < 4; ++r) {
            float tmax = fmaxf(Sv[0][r], Sv[1][r]);
#pragma unroll
            for (int off = 1; off < 16; off <<= 1)
                tmax = fmaxf(tmax, __shfl_xor(tmax, off, 64));
            const float mn = fmaxf(m_i[r], tmax);
            const float a  = __expf(m_i[r] - mn);
            const float p0 = __expf(Sv[0][r] - mn);
            const float p1 = __expf(Sv[1][r] - mn);
            Sv[0][r] = p0; Sv[1][r] = p1;
            float rs = p0 + p1;
#pragma unroll
            for (int off = 1; off < 16; off <<= 1)
                rs += __shfl_xor(rs, off, 64);
            l_i[r] = l_i[r] * a + rs;
            m_i[r] = mn;
            alpha[r] = a;
        }
#pragma unroll
        for (int t = 0; t < 8; ++t)
#pragma unroll
            for (int r = 0; r < 4; ++r)
                O[t][r] *= alpha[r];

        // ---- P: C-layout -> A-layout via per-wave LDS round-trip ----
#pragma unroll
        for (int r = 0; r < 4; ++r) {
            sPw[(quad * 4 + r) * PSTR + m]      = (__bf16)Sv[0][r];
            sPw[(quad * 4 + r) * PSTR + 16 + m] = (__bf16)Sv[1][r];
        }
        __asm__ volatile("s_waitcnt lgkmcnt(0)" ::: "memory");
        bf16x8 pf = *(const bf16x8*)&sPw[m * PSTR + quad * 8];

        // ---- O += P·V ----
#pragma unroll
        for (int t = 0; t < 8; ++t) {
            bf16x8 vf = *(const bf16x8*)&sVt[(t * 16 + m) * VSTR + quad * 8];
            O[t] = __builtin_amdgcn_mfma_f32_16x16x32_bf16(pf, vf, O[t], 0, 0, 0);
        }
        __syncthreads();
    }

    // ---- epilogue: normalize, padding-mask over D, store fp32 ----
    float inv[4];
#pragma unroll
    for (int r = 0; r < 4; ++r) inv[r] = 1.0f / l_i[r];
    const int qrow0 = qt * 64 + w * 16 + quad * 4;
    float* outp = Out + ((size_t)(bh * SQ_ + qrow0)) * D_;
#pragma unroll
    for (int t = 0; t < 8; ++t) {
        const int d = t * 16 + m;
        const float mk = (mask[d] != 0) ? 0.0f : 1.0f;
#pragma unroll
        for (int r = 0; r < 4; ++r)
            outp[r * D_ + d] = O[t][r] * inv[r] * mk;
    }
}

extern "C" void kernel_launch(void* const* d_in, const int* in_sizes, int n_in,
                              void* d_out, int out_size, void* d_ws, size_t ws_size,
                              hipStream_t stream) {
    const float* Q = (const float*)d_in[0];
    const float* K = (const float*)d_in[1];
    const float* V = (const float*)d_in[2];
    const int* mask = (const int*)d_in[3];
    float* out = (float*)d_out;
    dim3 grid(SQ_ / 64, 2 * 16);
    dim3 block(256);
    fattn_kernel<<<grid, block, 0, stream>>>(Q, K, V, mask, out);
}

// Round 3
// 357.831 us; speedup vs baseline: 1.2255x; 1.2255x over previous
//
#include <hip/hip_runtime.h>
#include <math.h>

#define SQ_ 2048
#define SK_ 2048
#define D_  128
#define BH_ 32
#define SCALE 20.0f

typedef __attribute__((ext_vector_type(8))) __bf16 bf16x8;
typedef __attribute__((ext_vector_type(4))) __bf16 bf16x4;
typedef __attribute__((ext_vector_type(2))) __bf16 bf16x2;
typedef __attribute__((ext_vector_type(4))) float  floatx4;

#define KSTR 136   // K LDS row stride elems (272B, 16B-aligned)
#define VSTR 40    // Vt LDS row stride elems (80B)
#define PSTR 40    // P LDS row stride elems (80B, 16B-aligned)

#define WS_KHI 0
#define WS_KLO ((size_t)BH_ * SK_ * D_)
#define WS_VT  ((size_t)2 * BH_ * SK_ * D_)
#define WS_NEED ((size_t)3 * BH_ * SK_ * D_ * 2)   // 50,331,648 B

// ---------------- pre-pass: K -> (Khi, Klo) bf16, same flat layout ----------------
__global__ void prep_k(const float* __restrict__ K, __bf16* __restrict__ Khi,
                       __bf16* __restrict__ Klo)
{
    size_t i = (size_t)blockIdx.x * 256 + threadIdx.x;   // grid 2048*256
#pragma unroll
    for (int r = 0; r < 4; ++r, i += 524288) {
        floatx4 v = ((const floatx4*)K)[i];
        bf16x4 h4, l4;
#pragma unroll
        for (int j = 0; j < 4; ++j) {
            __bf16 h = (__bf16)v[j];
            h4[j] = h;
            l4[j] = (__bf16)(v[j] - (float)h);
        }
        ((bf16x4*)Khi)[i] = h4;
        ((bf16x4*)Klo)[i] = l4;
    }
}

// ------------- pre-pass: V -> Vt tiles [bh][kt][d 128][key 32] bf16 -------------
__global__ void prep_v(const float* __restrict__ V, __bf16* __restrict__ Vt)
{
    __shared__ float sV[32 * 132];
    const int tid = threadIdx.x;
    const int kt = blockIdx.x & 63;
    const int bh = blockIdx.x >> 6;
    const float* src = V + ((size_t)bh * SK_ + kt * 32) * D_;
#pragma unroll
    for (int i = 0; i < 4; ++i) {
        int g = i * 256 + tid;               // 1024 granules of 4 floats
        int key = g >> 5, d4 = (g & 31) * 4;
        floatx4 v = *(const floatx4*)(src + key * D_ + d4);
        *(floatx4*)&sV[key * 132 + d4] = v;
    }
    __syncthreads();
    const int d = tid >> 1, half = tid & 1;
    bf16x8 a, b;
#pragma unroll
    for (int k = 0; k < 8; ++k) a[k] = (__bf16)sV[(half * 16 + k) * 132 + d];
#pragma unroll
    for (int k = 0; k < 8; ++k) b[k] = (__bf16)sV[(half * 16 + 8 + k) * 132 + d];
    __bf16* dst = Vt + (((size_t)(bh * 64 + kt) * 128 + d) * 32) + half * 16;
    *(bf16x8*)dst = a;
    *(bf16x8*)(dst + 8) = b;
}

// ---------------- main: 128-row q-tile, M=32/wave, pre-converted K/V ----------------
__global__ __launch_bounds__(256, 2)
void fattn2(const float* __restrict__ Q, const __bf16* __restrict__ Khi,
            const __bf16* __restrict__ Klo, const __bf16* __restrict__ Vt,
            const int* __restrict__ mask, float* __restrict__ Out)
{
    __shared__ __align__(16) __bf16 sKhi[32 * KSTR];
    __shared__ __align__(16) __bf16 sKlo[32 * KSTR];
    __shared__ __align__(16) __bf16 sVt[128 * VSTR];
    __shared__ __align__(16) __bf16 sP[4 * 32 * PSTR];

    const int tid  = threadIdx.x;
    const int w    = tid >> 6;
    const int lane = tid & 63;
    const int m    = lane & 15;
    const int quad = lane >> 4;
    // XCD-aware swizzle: 512 blocks, xcd = id&7 owns bh = xcd*4 .. +3
    const int id = blockIdx.x;
    const int bh = (id & 7) * 4 + ((id >> 3) & 3);
    const int qt = id >> 5;                 // 0..15, 128-row tiles

    // ---- Q A-fragments, hi/lo split, scale folded; 2 row-tiles per wave ----
    bf16x8 qhi[2][4], qlo[2][4];
#pragma unroll
    for (int rt = 0; rt < 2; ++rt) {
        const int qrow = qt * 128 + w * 32 + rt * 16 + m;
        const float* qp = Q + ((size_t)(bh * SQ_ + qrow)) * D_;
#pragma unroll
        for (int c = 0; c < 4; ++c) {
            const int d0 = c * 32 + quad * 8;
            floatx4 a = *(const floatx4*)(qp + d0);
            floatx4 b = *(const floatx4*)(qp + d0 + 4);
#pragma unroll
            for (int j = 0; j < 4; ++j) {
                float x = a[j] * SCALE;
                __bf16 h = (__bf16)x;
                qhi[rt][c][j] = h;
                qlo[rt][c][j] = (__bf16)(x - (float)h);
            }
#pragma unroll
            for (int j = 0; j < 4; ++j) {
                float x = b[j] * SCALE;
                __bf16 h = (__bf16)x;
                qhi[rt][c][4 + j] = h;
                qlo[rt][c][4 + j] = (__bf16)(x - (float)h);
            }
        }
    }

    floatx4 O[2][8];
#pragma unroll
    for (int rt = 0; rt < 2; ++rt)
#pragma unroll
        for (int t = 0; t < 8; ++t) O[rt][t] = (floatx4){0.f, 0.f, 0.f, 0.f};
    float m_i[2][4], l_i[2][4];
#pragma unroll
    for (int rt = 0; rt < 2; ++rt)
#pragma unroll
        for (int r = 0; r < 4; ++r) { m_i[rt][r] = -INFINITY; l_i[rt][r] = 0.f; }

    const __bf16* KhiB = Khi + (size_t)bh * SK_ * D_;
    const __bf16* KloB = Klo + (size_t)bh * SK_ * D_;
    const __bf16* VtB  = Vt  + (size_t)bh * SK_ * D_;
    __bf16* sPw = sP + w * 32 * PSTR;

    for (int kt = 0; kt < SK_ / 32; ++kt) {
        // ---- stage pre-converted tiles: 6 b128 loads + 6 b128 LDS stores ----
        const __bf16* kh_t = KhiB + kt * 32 * D_;
        const __bf16* kl_t = KloB + kt * 32 * D_;
        const __bf16* vt_t = VtB + (size_t)kt * 4096;
#pragma unroll
        for (int i = 0; i < 2; ++i) {
            const int g = i * 256 + tid;
            const int key = g >> 4, dk = (g & 15) * 8;
            *(bf16x8*)&sKhi[key * KSTR + dk] = *(const bf16x8*)(kh_t + g * 8);
            *(bf16x8*)&sKlo[key * KSTR + dk] = *(const bf16x8*)(kl_t + g * 8);
            const int dv = g >> 2, kb = (g & 3) * 8;
            *(bf16x8*)&sVt[dv * VSTR + kb] = *(const bf16x8*)(vt_t + g * 8);
        }
        __syncthreads();

        // ---- S = (20*Q)·K^T, split-precision; K frags reused across rt ----
        floatx4 S[2][2];
#pragma unroll
        for (int rt = 0; rt < 2; ++rt)
#pragma unroll
            for (int nt = 0; nt < 2; ++nt) S[rt][nt] = (floatx4){0.f, 0.f, 0.f, 0.f};
#pragma unroll
        for (int nt = 0; nt < 2; ++nt) {
#pragma unroll
            for (int c = 0; c < 4; ++c) {
                const int off = (nt * 16 + m) * KSTR + c * 32 + quad * 8;
                bf16x8 kh = *(const bf16x8*)&sKhi[off];
                bf16x8 kl = *(const bf16x8*)&sKlo[off];
#pragma unroll
                for (int rt = 0; rt < 2; ++rt) {
                    S[rt][nt] = __builtin_amdgcn_mfma_f32_16x16x32_bf16(qhi[rt][c], kh, S[rt][nt], 0, 0, 0);
                    S[rt][nt] = __builtin_amdgcn_mfma_f32_16x16x32_bf16(qlo[rt][c], kh, S[rt][nt], 0, 0, 0);
                    S[rt][nt] = __builtin_amdgcn_mfma_f32_16x16x32_bf16(qhi[rt][c], kl, S[rt][nt], 0, 0, 0);
                }
            }
        }

        // ---- online softmax ----
        float alpha[2][4];
#pragma unroll
        for (int rt = 0; rt < 2; ++rt) {
#pragma unroll
            for (int r = 0; r < 4; ++r) {
                float tmax = fmaxf(S[rt][0][r], S[rt][1][r]);
#pragma unroll
                for (int off = 1; off < 16; off <<= 1)
                    tmax = fmaxf(tmax, __shfl_xor(tmax, off, 64));
                const float mn = fmaxf(m_i[rt][r], tmax);
                const float a  = __expf(m_i[rt][r] - mn);
                const float p0 = __expf(S[rt][0][r] - mn);
                const float p1 = __expf(S[rt][1][r] - mn);
                S[rt][0][r] = p0; S[rt][1][r] = p1;
                float rs = p0 + p1;
#pragma unroll
                for (int off = 1; off < 16; off <<= 1)
                    rs += __shfl_xor(rs, off, 64);
                l_i[rt][r] = l_i[rt][r] * a + rs;
                m_i[rt][r] = mn;
                alpha[rt][r] = a;
            }
#pragma unroll
            for (int t = 0; t < 8; ++t)
#pragma unroll
                for (int r = 0; r < 4; ++r)
                    O[rt][t][r] *= alpha[rt][r];
        }

        // ---- P: C-layout -> A-layout via per-wave LDS round-trip ----
#pragma unroll
        for (int rt = 0; rt < 2; ++rt)
#pragma unroll
            for (int r = 0; r < 4; ++r) {
                sPw[(rt * 16 + quad * 4 + r) * PSTR + m]      = (__bf16)S[rt][0][r];
                sPw[(rt * 16 + quad * 4 + r) * PSTR + 16 + m] = (__bf16)S[rt][1][r];
            }
        __asm__ volatile("s_waitcnt lgkmcnt(0)" ::: "memory");
        bf16x8 pf0 = *(const bf16x8*)&sPw[m * PSTR + quad * 8];
        bf16x8 pf1 = *(const bf16x8*)&sPw[(16 + m) * PSTR + quad * 8];

        // ---- O += P·V, V frags reused across rt ----
#pragma unroll
        for (int t = 0; t < 8; ++t) {
            bf16x8 vf = *(const bf16x8*)&sVt[(t * 16 + m) * VSTR + quad * 8];
            O[0][t] = __builtin_amdgcn_mfma_f32_16x16x32_bf16(pf0, vf, O[0][t], 0, 0, 0);
            O[1][t] = __builtin_amdgcn_mfma_f32_16x16x32_bf16(pf1, vf, O[1][t], 0, 0, 0);
        }
        __syncthreads();
    }

    // ---- epilogue ----
#pragma unroll
    for (int rt = 0; rt < 2; ++rt) {
        float inv[4];
#pragma unroll
        for (int r = 0; r < 4; ++r) inv[r] = 1.0f / l_i[rt][r];
        const int qrow0 = qt * 128 + w * 32 + rt * 16 + quad * 4;
        float* outp = Out + ((size_t)(bh * SQ_ + qrow0)) * D_;
#pragma unroll
        for (int t = 0; t < 8; ++t) {
            const int d = t * 16 + m;
            const float mk = (mask[d] != 0) ? 0.0f : 1.0f;
#pragma unroll
            for (int r = 0; r < 4; ++r)
                outp[r * D_ + d] = O[rt][t][r] * inv[r] * mk;
        }
    }
}

// ---------------- fallback (R2 kernel, known-passing) if ws too small ----------------
__global__ __launch_bounds__(256, 2)
void fattn_kernel(const float* __restrict__ Q, const float* __restrict__ K,
                  const float* __restrict__ V, const int* __restrict__ mask,
                  float* __restrict__ Out)
{
    __shared__ __align__(16) __bf16 sKhi[32 * KSTR];
    __shared__ __align__(16) __bf16 sKlo[32 * KSTR];
    __shared__ __align__(16) __bf16 sVt[128 * VSTR];
    __shared__ __align__(16) __bf16 sP[4 * 16 * PSTR];

    const int tid  = threadIdx.x;
    const int w    = tid >> 6;
    const int lane = tid & 63;
    const int m    = lane & 15;
    const int quad = lane >> 4;
    const int qt   = blockIdx.x;
    const int bh   = blockIdx.y;

    bf16x8 qhi[4], qlo[4];
    {
        const int qrow = qt * 64 + w * 16 + m;
        const float* qp = Q + ((size_t)(bh * SQ_ + qrow)) * D_;
#pragma unroll
        for (int c = 0; c < 4; ++c) {
            const int d0 = c * 32 + quad * 8;
            floatx4 a = *(const floatx4*)(qp + d0);
            floatx4 b = *(const floatx4*)(qp + d0 + 4);
#pragma unroll
            for (int j = 0; j < 4; ++j) {
                float x = a[j] * SCALE;
                __bf16 h = (__bf16)x;
                qhi[c][j] = h;
                qlo[c][j] = (__bf16)(x - (float)h);
            }
#pragma unroll
            for (int j = 0; j < 4; ++j) {
                float x = b[j] * SCALE;
                __bf16 h = (__bf16)x;
                qhi[c][4 + j] = h;
                qlo[c][4 + j] = (__bf16)(x - (float)h);
            }
        }
    }

    floatx4 O[8];
#pragma unroll
    for (int t = 0; t < 8; ++t) O[t] = (floatx4){0.f, 0.f, 0.f, 0.f};
    float m_i[4] = {-INFINITY, -INFINITY, -INFINITY, -INFINITY};
    float l_i[4] = {0.f, 0.f, 0.f, 0.f};

    const float* Kbh = K + (size_t)bh * SK_ * D_;
    const float* Vbh = V + (size_t)bh * SK_ * D_;
    __bf16* sPw = sP + w * 16 * PSTR;

    for (int kt = 0; kt < SK_ / 32; ++kt) {
        const int kbase = kt * 32;
#pragma unroll
        for (int i = 0; i < 4; ++i) {
            const int lin = i * 1024 + tid * 4;
            const int key = lin >> 7;
            const int d   = lin & 127;
            floatx4 v = *(const floatx4*)(Kbh + (kbase + key) * D_ + d);
            bf16x4 h4, l4;
#pragma unroll
            for (int j = 0; j < 4; ++j) {
                __bf16 h = (__bf16)v[j];
                h4[j] = h;
                l4[j] = (__bf16)(v[j] - (float)h);
            }
            *(bf16x4*)&sKhi[key * KSTR + d] = h4;
            *(bf16x4*)&sKlo[key * KSTR + d] = l4;
        }
#pragma unroll
        for (int i = 0; i < 2; ++i) {
            const int pi   = i * 256 + tid;
            const int kp   = (pi & 15) * 2;
            const int dblk = (pi >> 4);
            const int d0   = dblk * 4;
            floatx4 v0 = *(const floatx4*)(Vbh + (kbase + kp) * D_ + d0);
            floatx4 v1 = *(const floatx4*)(Vbh + (kbase + kp + 1) * D_ + d0);
#pragma unroll
            for (int j = 0; j < 4; ++j) {
                bf16x2 p2;
                p2[0] = (__bf16)v0[j];
                p2[1] = (__bf16)v1[j];
                *(bf16x2*)&sVt[(d0 + j) * VSTR + kp] = p2;
            }
        }
        __syncthreads();

        floatx4 Sv[2];
#pragma unroll
        for (int nt = 0; nt < 2; ++nt) {
            floatx4 acc = (floatx4){0.f, 0.f, 0.f, 0.f};
#pragma unroll
            for (int c = 0; c < 4; ++c) {
                const int off = (nt * 16 + m) * KSTR + c * 32 + quad * 8;
                bf16x8 kh = *(const bf16x8*)&sKhi[off];
                bf16x8 kl = *(const bf16x8*)&sKlo[off];
                acc = __builtin_amdgcn_mfma_f32_16x16x32_bf16(qhi[c], kh, acc, 0, 0, 0);
                acc = __builtin_amdgcn_mfma_f32_16x16x32_bf16(qlo[c], kh, acc, 0, 0, 0);
                acc = __builtin_amdgcn_mfma_f32_16x16x32_bf16(qhi[c], kl, acc, 0, 0, 0);
            }
            Sv[nt] = acc;
        }

        float alpha[4];
#pragma unroll
        for (int r = 0; r < 4; ++r) {
            float tmax = fmaxf(Sv[0][r], Sv[1][r]);
#pragma unroll
            for (int off = 1; off < 16; off <<= 1)
                tmax = fmaxf(tmax, __shfl_xor(tmax, off, 64));
            const float mn = fmaxf(m_i[r], tmax);
            const float a  = __expf(m_i[r] - mn);
            const float p0 = __expf(Sv[0][r] - mn);
            const float p1 = __expf(Sv[1][r] - mn);
            Sv[0][r] = p0; Sv[1][r] = p1;
            float rs = p0 + p1;
#pragma unroll
            for (int off = 1; off < 16; off <<= 1)
                rs += __shfl_xor(rs, off, 64);
            l_i[r] = l_i[r] * a + rs;
            m_i[r] = mn;
            alpha[r] = a;
        }
#pragma unroll
        for (int t = 0; t < 8; ++t)
#pragma unroll
            for (int r = 0; r < 4; ++r)
                O[t][r] *= alpha[r];

#pragma unroll
        for (int r = 0; r < 4; ++r) {
            sPw[(quad * 4 + r) * PSTR + m]      = (__bf16)Sv[0][r];
            sPw[(quad * 4 + r) * PSTR + 16 + m] = (__bf16)Sv[1][r];
        }
        __asm__ volatile("s_waitcnt lgkmcnt(0)" ::: "memory");
        bf16x8 pf = *(const bf16x8*)&sPw[m * PSTR + quad * 8];

#pragma unroll
        for (int t = 0; t < 8; ++t) {
            bf16x8 vf = *(const bf16x8*)&sVt[(t * 16 + m) * VSTR + quad * 8];
            O[t] = __builtin_amdgcn_mfma_f32_16x16x32_bf16(pf, vf, O[t], 0, 0, 0);
        }
        __syncthreads();
    }

    float inv[4];
#pragma unroll
    for (int r = 0; r < 4; ++r) inv[r] = 1.0f / l_i[r];
    const int qrow0 = qt * 64 + w * 16 + quad * 4;
    float* outp = Out + ((size_t)(bh * SQ_ + qrow0)) * D_;
#pragma unroll
    for (int t = 0; t < 8; ++t) {
        const int d = t * 16 + m;
        const float mk = (mask[d] != 0) ? 0.0f : 1.0f;
#pragma unroll
        for (int r = 0; r < 4; ++r)
            outp[r * D_ + d] = O[t][r] * inv[r] * mk;
    }
}

extern "C" void kernel_launch(void* const* d_in, const int* in_sizes, int n_in,
                              void* d_out, int out_size, void* d_ws, size_t ws_size,
                              hipStream_t stream) {
    const float* Q = (const float*)d_in[0];
    const float* K = (const float*)d_in[1];
    const float* V = (const float*)d_in[2];
    const int* mask = (const int*)d_in[3];
    float* out = (float*)d_out;

    if (ws_size >= WS_NEED) {
        __bf16* Khi = (__bf16*)d_ws + WS_KHI;
        __bf16* Klo = (__bf16*)d_ws + WS_KLO;
        __bf16* Vt  = (__bf16*)d_ws + WS_VT;
        prep_k<<<2048, 256, 0, stream>>>(K, Khi, Klo);
        prep_v<<<2048, 256, 0, stream>>>(V, Vt);
        fattn2<<<512, 256, 0, stream>>>(Q, Khi, Klo, Vt, mask, out);
    } else {
        dim3 grid(SQ_ / 64, BH_);
        fattn_kernel<<<grid, 256, 0, stream>>>(Q, K, V, mask, out);
    }
}

// Round 4
// 300.814 us; speedup vs baseline: 1.4577x; 1.1895x over previous
//
#include <hip/hip_runtime.h>
#include <math.h>

#define SQ_ 2048
#define SK_ 2048
#define D_  128
#define BH_ 32
#define SCALE 20.0f

typedef __attribute__((ext_vector_type(8))) __bf16 bf16x8;
typedef __attribute__((ext_vector_type(4))) __bf16 bf16x4;
typedef __attribute__((ext_vector_type(2))) __bf16 bf16x2;
typedef __attribute__((ext_vector_type(4))) float  floatx4;

#define PSTR 40    // P LDS row stride elems (80B, 16B-aligned, conflict-free reads)
#define TILE_ELEMS 12288   // 24KB per (bh,kt) tile: Khi 8KB | Klo 8KB | Vt 8KB
#define WS_NEED ((size_t)BH_ * 64 * TILE_ELEMS * 2)   // 50,331,648 B

// ---------- async 16B global->LDS (dest = uniform base + lane*16) ----------
typedef __attribute__((address_space(3))) unsigned int lds_uint;
typedef const __attribute__((address_space(1))) unsigned int glob_uint;
__device__ __forceinline__ void async16(const void* g, void* l) {
    __builtin_amdgcn_global_load_lds((glob_uint*)g, (lds_uint*)l, 16, 0, 0);
}

// ---------- 16-lane max reduction on the VALU pipe via DPP ----------
template<int CTRL>
__device__ __forceinline__ float dpp_maxstep(float x) {
    int xi = __builtin_bit_cast(int, x);
    int yi = __builtin_amdgcn_update_dpp(xi, xi, CTRL, 0xF, 0xF, false);
    return fmaxf(x, __builtin_bit_cast(float, yi));
}
__device__ __forceinline__ float rowmax16(float x) {
    x = dpp_maxstep<0xB1>(x);    // quad_perm [1,0,3,2]  (xor 1)
    x = dpp_maxstep<0x4E>(x);    // quad_perm [2,3,0,1]  (xor 2)
    x = dpp_maxstep<0x141>(x);   // row_half_mirror
    x = dpp_maxstep<0x140>(x);   // row_mirror
    return x;
}

// ---------- pre-pass: K -> tiled (Khi|Klo) in LDS-granule order ----------
// granule (c4q*32 + key) <-> K[key][c4q*8 .. +8]; src linear in thread id.
__global__ void prep_k2(const float* __restrict__ K, __bf16* __restrict__ ws)
{
    const int kt = blockIdx.x & 63, bh = blockIdx.x >> 6;
    const int t = threadIdx.x;
    const float* src = K + ((size_t)(bh * SK_ + kt * 32)) * D_;
    __bf16* tile = ws + (size_t)(bh * 64 + kt) * TILE_ELEMS;
#pragma unroll
    for (int h = 0; h < 2; ++h) {
        const int tt = t + h * 256;          // 0..511
        const int key = tt >> 4, c4q = tt & 15;
        floatx4 a = *(const floatx4*)(src + tt * 8);
        floatx4 b = *(const floatx4*)(src + tt * 8 + 4);
        bf16x8 hi, lo;
#pragma unroll
        for (int j = 0; j < 4; ++j) {
            __bf16 x = (__bf16)a[j]; hi[j] = x; lo[j] = (__bf16)(a[j] - (float)x);
        }
#pragma unroll
        for (int j = 0; j < 4; ++j) {
            __bf16 x = (__bf16)b[j]; hi[4 + j] = x; lo[4 + j] = (__bf16)(b[j] - (float)x);
        }
        const int g = c4q * 32 + key;
        *(bf16x8*)(tile + g * 8) = hi;
        *(bf16x8*)(tile + 4096 + g * 8) = lo;
    }
}

// ---------- pre-pass: V -> Vt tiles, granule (quad*128 + d) <-> V[quad*8+e][d] ----------
__global__ void prep_v2(const float* __restrict__ V, __bf16* __restrict__ ws)
{
    const int kt = blockIdx.x & 63, bh = blockIdx.x >> 6;
    const int t = threadIdx.x;
    const float* src = V + ((size_t)(bh * SK_ + kt * 32)) * D_;
    __bf16* tile = ws + (size_t)(bh * 64 + kt) * TILE_ELEMS + 8192;
#pragma unroll
    for (int h = 0; h < 2; ++h) {
        const int g = t + h * 256;           // 0..511
        const int d = g & 127, quad = g >> 7;
        bf16x8 p;
#pragma unroll
        for (int e = 0; e < 8; ++e)
            p[e] = (__bf16)src[(quad * 8 + e) * D_ + d];
        *(bf16x8*)(tile + g * 8) = p;
    }
}

// ---------- main kernel: DMA double-buffer, M=32/wave, DPP max, ones-MFMA sum ----------
__global__ __launch_bounds__(256, 2)
void fattn3(const float* __restrict__ Q, const __bf16* __restrict__ ws,
            const int* __restrict__ mask, float* __restrict__ Out)
{
    __shared__ __align__(16) __bf16 sTile[2][TILE_ELEMS];
    __shared__ __align__(16) __bf16 sP[4 * 32 * PSTR];

    const int tid  = threadIdx.x;
    const int w    = tid >> 6;
    const int lane = tid & 63;
    const int m    = lane & 15;
    const int quad = lane >> 4;
    const int id = blockIdx.x;
    const int bh = (id & 7) * 4 + ((id >> 3) & 3);   // XCD swizzle
    const int qt = id >> 5;

    // ---- Q A-fragments, hi/lo split of 20*q ----
    bf16x8 qhi[2][4], qlo[2][4];
#pragma unroll
    for (int rt = 0; rt < 2; ++rt) {
        const int qrow = qt * 128 + w * 32 + rt * 16 + m;
        const float* qp = Q + ((size_t)(bh * SQ_ + qrow)) * D_;
#pragma unroll
        for (int c = 0; c < 4; ++c) {
            const int d0 = c * 32 + quad * 8;
            floatx4 a = *(const floatx4*)(qp + d0);
            floatx4 b = *(const floatx4*)(qp + d0 + 4);
#pragma unroll
            for (int j = 0; j < 4; ++j) {
                float x = a[j] * SCALE;
                __bf16 h = (__bf16)x;
                qhi[rt][c][j] = h; qlo[rt][c][j] = (__bf16)(x - (float)h);
            }
#pragma unroll
            for (int j = 0; j < 4; ++j) {
                float x = b[j] * SCALE;
                __bf16 h = (__bf16)x;
                qhi[rt][c][4 + j] = h; qlo[rt][c][4 + j] = (__bf16)(x - (float)h);
            }
        }
    }

    bf16x8 vones;
#pragma unroll
    for (int j = 0; j < 8; ++j) vones[j] = (__bf16)1.0f;

    floatx4 O[2][8], lac[2];
#pragma unroll
    for (int rt = 0; rt < 2; ++rt) {
        lac[rt] = (floatx4){0.f, 0.f, 0.f, 0.f};
#pragma unroll
        for (int t = 0; t < 8; ++t) O[rt][t] = (floatx4){0.f, 0.f, 0.f, 0.f};
    }
    float m_i[2][4];
#pragma unroll
    for (int rt = 0; rt < 2; ++rt)
#pragma unroll
        for (int r = 0; r < 4; ++r) m_i[rt][r] = -INFINITY;

    const __bf16* wsB = ws + (size_t)bh * 64 * TILE_ELEMS;
    __bf16* sPw = sP + w * 32 * PSTR;

    // prologue: DMA tile 0 into buf 0 (6 x 1KB per wave)
#pragma unroll
    for (int j6 = 0; j6 < 6; ++j6) {
        const int j = w * 6 + j6;
        async16(wsB + j * 512 + lane * 8, &sTile[0][j * 512]);
    }

    for (int kt = 0; kt < SK_ / 32; ++kt) {
        const int buf = kt & 1;
        __syncthreads();   // drains own vmcnt (DMA for buf) then barrier

        if (kt < SK_ / 32 - 1) {
            const __bf16* wsT = wsB + (size_t)(kt + 1) * TILE_ELEMS;
#pragma unroll
            for (int j6 = 0; j6 < 6; ++j6) {
                const int j = w * 6 + j6;
                async16(wsT + j * 512 + lane * 8, &sTile[buf ^ 1][j * 512]);
            }
        }

        const __bf16* khi = &sTile[buf][0];
        const __bf16* klo = khi + 4096;
        const __bf16* vt  = khi + 8192;

        // ---- S = (20*Q)·K^T, split precision ----
        floatx4 S[2][2];
#pragma unroll
        for (int rt = 0; rt < 2; ++rt)
#pragma unroll
            for (int nt = 0; nt < 2; ++nt) S[rt][nt] = (floatx4){0.f, 0.f, 0.f, 0.f};
#pragma unroll
        for (int nt = 0; nt < 2; ++nt) {
#pragma unroll
            for (int c = 0; c < 4; ++c) {
                const int off = (((c * 4 + quad) * 32) + nt * 16 + m) * 8;
                bf16x8 kh = *(const bf16x8*)(khi + off);
                bf16x8 kl = *(const bf16x8*)(klo + off);
#pragma unroll
                for (int rt = 0; rt < 2; ++rt) {
                    S[rt][nt] = __builtin_amdgcn_mfma_f32_16x16x32_bf16(qhi[rt][c], kh, S[rt][nt], 0, 0, 0);
                    S[rt][nt] = __builtin_amdgcn_mfma_f32_16x16x32_bf16(qlo[rt][c], kh, S[rt][nt], 0, 0, 0);
                    S[rt][nt] = __builtin_amdgcn_mfma_f32_16x16x32_bf16(qhi[rt][c], kl, S[rt][nt], 0, 0, 0);
                }
            }
        }

        // ---- online softmax: DPP row-max, exp, rescale ----
#pragma unroll
        for (int rt = 0; rt < 2; ++rt) {
            float alpha[4];
#pragma unroll
            for (int r = 0; r < 4; ++r) {
                const float tmax = rowmax16(fmaxf(S[rt][0][r], S[rt][1][r]));
                const float mn = fmaxf(m_i[rt][r], tmax);
                alpha[r] = __expf(m_i[rt][r] - mn);
                S[rt][0][r] = __expf(S[rt][0][r] - mn);
                S[rt][1][r] = __expf(S[rt][1][r] - mn);
                m_i[rt][r] = mn;
            }
#pragma unroll
            for (int r = 0; r < 4; ++r) lac[rt][r] *= alpha[r];
#pragma unroll
            for (int t = 0; t < 8; ++t)
#pragma unroll
                for (int r = 0; r < 4; ++r)
                    O[rt][t][r] *= alpha[r];
        }

        // ---- P: C-layout -> A-layout via per-wave LDS round-trip ----
#pragma unroll
        for (int rt = 0; rt < 2; ++rt)
#pragma unroll
            for (int r = 0; r < 4; ++r) {
                sPw[(rt * 16 + quad * 4 + r) * PSTR + m]      = (__bf16)S[rt][0][r];
                sPw[(rt * 16 + quad * 4 + r) * PSTR + 16 + m] = (__bf16)S[rt][1][r];
            }
        __asm__ volatile("s_waitcnt lgkmcnt(0)" ::: "memory");
        bf16x8 pf0 = *(const bf16x8*)&sPw[m * PSTR + quad * 8];
        bf16x8 pf1 = *(const bf16x8*)&sPw[(16 + m) * PSTR + quad * 8];

        // ---- row-sums via ones-MFMA; O += P·V ----
        lac[0] = __builtin_amdgcn_mfma_f32_16x16x32_bf16(pf0, vones, lac[0], 0, 0, 0);
        lac[1] = __builtin_amdgcn_mfma_f32_16x16x32_bf16(pf1, vones, lac[1], 0, 0, 0);
#pragma unroll
        for (int t = 0; t < 8; ++t) {
            bf16x8 vf = *(const bf16x8*)(vt + (quad * 128 + t * 16 + m) * 8);
            O[0][t] = __builtin_amdgcn_mfma_f32_16x16x32_bf16(pf0, vf, O[0][t], 0, 0, 0);
            O[1][t] = __builtin_amdgcn_mfma_f32_16x16x32_bf16(pf1, vf, O[1][t], 0, 0, 0);
        }
    }

    // ---- epilogue ----
#pragma unroll
    for (int rt = 0; rt < 2; ++rt) {
        float inv[4];
#pragma unroll
        for (int r = 0; r < 4; ++r) inv[r] = 1.0f / lac[rt][r];
        const int qrow0 = qt * 128 + w * 32 + rt * 16 + quad * 4;
        float* outp = Out + ((size_t)(bh * SQ_ + qrow0)) * D_;
#pragma unroll
        for (int t = 0; t < 8; ++t) {
            const int d = t * 16 + m;
            const float mk = (mask[d] != 0) ? 0.0f : 1.0f;
#pragma unroll
            for (int r = 0; r < 4; ++r)
                outp[r * D_ + d] = O[rt][t][r] * inv[r] * mk;
        }
    }
}

// ---------------- fallback (R2 kernel, known-passing) if ws too small ----------------
#define KSTR 136
#define VSTR 40
__global__ __launch_bounds__(256, 2)
void fattn_kernel(const float* __restrict__ Q, const float* __restrict__ K,
                  const float* __restrict__ V, const int* __restrict__ mask,
                  float* __restrict__ Out)
{
    __shared__ __align__(16) __bf16 sKhi[32 * KSTR];
    __shared__ __align__(16) __bf16 sKlo[32 * KSTR];
    __shared__ __align__(16) __bf16 sVt[128 * VSTR];
    __shared__ __align__(16) __bf16 sP2[4 * 16 * PSTR];

    const int tid  = threadIdx.x;
    const int w    = tid >> 6;
    const int lane = tid & 63;
    const int m    = lane & 15;
    const int quad = lane >> 4;
    const int qt   = blockIdx.x;
    const int bh   = blockIdx.y;

    bf16x8 qhi[4], qlo[4];
    {
        const int qrow = qt * 64 + w * 16 + m;
        const float* qp = Q + ((size_t)(bh * SQ_ + qrow)) * D_;
#pragma unroll
        for (int c = 0; c < 4; ++c) {
            const int d0 = c * 32 + quad * 8;
            floatx4 a = *(const floatx4*)(qp + d0);
            floatx4 b = *(const floatx4*)(qp + d0 + 4);
#pragma unroll
            for (int j = 0; j < 4; ++j) {
                float x = a[j] * SCALE;
                __bf16 h = (__bf16)x;
                qhi[c][j] = h; qlo[c][j] = (__bf16)(x - (float)h);
            }
#pragma unroll
            for (int j = 0; j < 4; ++j) {
                float x = b[j] * SCALE;
                __bf16 h = (__bf16)x;
                qhi[c][4 + j] = h; qlo[c][4 + j] = (__bf16)(x - (float)h);
            }
        }
    }

    floatx4 O[8];
#pragma unroll
    for (int t = 0; t < 8; ++t) O[t] = (floatx4){0.f, 0.f, 0.f, 0.f};
    float m_i[4] = {-INFINITY, -INFINITY, -INFINITY, -INFINITY};
    float l_i[4] = {0.f, 0.f, 0.f, 0.f};

    const float* Kbh = K + (size_t)bh * SK_ * D_;
    const float* Vbh = V + (size_t)bh * SK_ * D_;
    __bf16* sPw = sP2 + w * 16 * PSTR;

    for (int kt = 0; kt < SK_ / 32; ++kt) {
        const int kbase = kt * 32;
#pragma unroll
        for (int i = 0; i < 4; ++i) {
            const int lin = i * 1024 + tid * 4;
            const int key = lin >> 7;
            const int d   = lin & 127;
            floatx4 v = *(const floatx4*)(Kbh + (kbase + key) * D_ + d);
            bf16x4 h4, l4;
#pragma unroll
            for (int j = 0; j < 4; ++j) {
                __bf16 h = (__bf16)v[j]; h4[j] = h; l4[j] = (__bf16)(v[j] - (float)h);
            }
            *(bf16x4*)&sKhi[key * KSTR + d] = h4;
            *(bf16x4*)&sKlo[key * KSTR + d] = l4;
        }
#pragma unroll
        for (int i = 0; i < 2; ++i) {
            const int pi   = i * 256 + tid;
            const int kp   = (pi & 15) * 2;
            const int dblk = (pi >> 4);
            const int d0   = dblk * 4;
            floatx4 v0 = *(const floatx4*)(Vbh + (kbase + kp) * D_ + d0);
            floatx4 v1 = *(const floatx4*)(Vbh + (kbase + kp + 1) * D_ + d0);
#pragma unroll
            for (int j = 0; j < 4; ++j) {
                bf16x2 p2; p2[0] = (__bf16)v0[j]; p2[1] = (__bf16)v1[j];
                *(bf16x2*)&sVt[(d0 + j) * VSTR + kp] = p2;
            }
        }
        __syncthreads();

        floatx4 Sv[2];
#pragma unroll
        for (int nt = 0; nt < 2; ++nt) {
            floatx4 acc = (floatx4){0.f, 0.f, 0.f, 0.f};
#pragma unroll
            for (int c = 0; c < 4; ++c) {
                const int off = (nt * 16 + m) * KSTR + c * 32 + quad * 8;
                bf16x8 kh = *(const bf16x8*)&sKhi[off];
                bf16x8 kl = *(const bf16x8*)&sKlo[off];
                acc = __builtin_amdgcn_mfma_f32_16x16x32_bf16(qhi[c], kh, acc, 0, 0, 0);
                acc = __builtin_amdgcn_mfma_f32_16x16x32_bf16(qlo[c], kh, acc, 0, 0, 0);
                acc = __builtin_amdgcn_mfma_f32_16x16x32_bf16(qhi[c], kl, acc, 0, 0, 0);
            }
            Sv[nt] = acc;
        }

        float alpha[4];
#pragma unroll
        for (int r = 0; r < 4; ++r) {
            float tmax = fmaxf(Sv[0][r], Sv[1][r]);
#pragma unroll
            for (int off = 1; off < 16; off <<= 1)
                tmax = fmaxf(tmax, __shfl_xor(tmax, off, 64));
            const float mn = fmaxf(m_i[r], tmax);
            const float a  = __expf(m_i[r] - mn);
            const float p0 = __expf(Sv[0][r] - mn);
            const float p1 = __expf(Sv[1][r] - mn);
            Sv[0][r] = p0; Sv[1][r] = p1;
            float rs = p0 + p1;
#pragma unroll
            for (int off = 1; off < 16; off <<= 1)
                rs += __shfl_xor(rs, off, 64);
            l_i[r] = l_i[r] * a + rs;
            m_i[r] = mn;
            alpha[r] = a;
        }
#pragma unroll
        for (int t = 0; t < 8; ++t)
#pragma unroll
            for (int r = 0; r < 4; ++r)
                O[t][r] *= alpha[r];

#pragma unroll
        for (int r = 0; r < 4; ++r) {
            sPw[(quad * 4 + r) * PSTR + m]      = (__bf16)Sv[0][r];
            sPw[(quad * 4 + r) * PSTR + 16 + m] = (__bf16)Sv[1][r];
        }
        __asm__ volatile("s_waitcnt lgkmcnt(0)" ::: "memory");
        bf16x8 pf = *(const bf16x8*)&sPw[m * PSTR + quad * 8];

#pragma unroll
        for (int t = 0; t < 8; ++t) {
            bf16x8 vf = *(const bf16x8*)&sVt[(t * 16 + m) * VSTR + quad * 8];
            O[t] = __builtin_amdgcn_mfma_f32_16x16x32_bf16(pf, vf, O[t], 0, 0, 0);
        }
        __syncthreads();
    }

    float inv[4];
#pragma unroll
    for (int r = 0; r < 4; ++r) inv[r] = 1.0f / l_i[r];
    const int qrow0 = qt * 64 + w * 16 + quad * 4;
    float* outp = Out + ((size_t)(bh * SQ_ + qrow0)) * D_;
#pragma unroll
    for (int t = 0; t < 8; ++t) {
        const int d = t * 16 + m;
        const float mk = (mask[d] != 0) ? 0.0f : 1.0f;
#pragma unroll
        for (int r = 0; r < 4; ++r)
            outp[r * D_ + d] = O[t][r] * inv[r] * mk;
    }
}

extern "C" void kernel_launch(void* const* d_in, const int* in_sizes, int n_in,
                              void* d_out, int out_size, void* d_ws, size_t ws_size,
                              hipStream_t stream) {
    const float* Q = (const float*)d_in[0];
    const float* K = (const float*)d_in[1];
    const float* V = (const float*)d_in[2];
    const int* mask = (const int*)d_in[3];
    float* out = (float*)d_out;

    if (ws_size >= WS_NEED) {
        __bf16* ws = (__bf16*)d_ws;
        prep_k2<<<2048, 256, 0, stream>>>(K, ws);
        prep_v2<<<2048, 256, 0, stream>>>(V, ws);
        fattn3<<<512, 256, 0, stream>>>(Q, ws, mask, out);
    } else {
        dim3 grid(SQ_ / 64, BH_);
        fattn_kernel<<<grid, 256, 0, stream>>>(Q, K, V, mask, out);
    }
}

// Round 5
// 276.021 us; speedup vs baseline: 1.5887x; 1.0898x over previous
//
#include <hip/hip_runtime.h>
#include <math.h>

#define SQ_ 2048
#define SK_ 2048
#define D_  128
#define BH_ 32
#define SCALE_L2E 28.853900817779268f   // 20 * log2(e): softmax done in exp2 domain
#define TAU 13.0f                       // lazy-rescale slack (P <= 2^13 < f16 max)

typedef _Float16 f16;
typedef __attribute__((ext_vector_type(8))) f16    f16x8;
typedef __attribute__((ext_vector_type(4))) f16    f16x4;
typedef __attribute__((ext_vector_type(4))) float  floatx4;
typedef __attribute__((ext_vector_type(8))) __bf16 bf16x8;
typedef __attribute__((ext_vector_type(4))) __bf16 bf16x4;
typedef __attribute__((ext_vector_type(2))) __bf16 bf16x2;

#define TILE_ELEMS 24576                 // 48KB: Khi 16KB | Klo 16KB | Vt 16KB
#define WS_NEED ((size_t)BH_ * 32 * TILE_ELEMS * 2)   // 50,331,648 B

typedef __attribute__((address_space(3))) unsigned int lds_uint;
typedef const __attribute__((address_space(1))) unsigned int glob_uint;
__device__ __forceinline__ void async16(const void* g, void* l) {
    __builtin_amdgcn_global_load_lds((glob_uint*)g, (lds_uint*)l, 16, 0, 0);
}

// ---- fused pre-pass: one block per (bh, 64-key tile) ----
// K granule g=(c4q*64+key) <-> K[key][c4q*8..+8] (hi|lo f16)
// V granule g=(kq*128+d)   <-> V[kq*8+e][d], e=0..7
__global__ void prep(const float* __restrict__ K, const float* __restrict__ V,
                     f16* __restrict__ ws)
{
    __shared__ float sB[64 * 132];
    const int id = blockIdx.x;           // bh*32 + kt
    const int t  = threadIdx.x;
    const size_t src_off = ((size_t)(id >> 5) * SK_ + (id & 31) * 64) * D_;
    f16* tile = ws + (size_t)id * TILE_ELEMS;

    const float* srcK = K + src_off;
#pragma unroll
    for (int i = 0; i < 8; ++i) {
        const int idx = t + i * 256, row = idx >> 5, c4 = (idx & 31) * 4;
        *(floatx4*)&sB[row * 132 + c4] = *(const floatx4*)(srcK + row * 128 + c4);
    }
    __syncthreads();
#pragma unroll
    for (int h = 0; h < 4; ++h) {
        const int g = t + h * 256, key = g & 63, c4q = g >> 6;
        floatx4 a = *(const floatx4*)&sB[key * 132 + c4q * 8];
        floatx4 b = *(const floatx4*)&sB[key * 132 + c4q * 8 + 4];
        f16x8 hi, lo;
#pragma unroll
        for (int j = 0; j < 4; ++j) {
            f16 x = (f16)a[j]; hi[j] = x; lo[j] = (f16)(a[j] - (float)x);
        }
#pragma unroll
        for (int j = 0; j < 4; ++j) {
            f16 x = (f16)b[j]; hi[4 + j] = x; lo[4 + j] = (f16)(b[j] - (float)x);
        }
        *(f16x8*)(tile + g * 8) = hi;
        *(f16x8*)(tile + 8192 + g * 8) = lo;
    }
    __syncthreads();
    const float* srcV = V + src_off;
#pragma unroll
    for (int i = 0; i < 8; ++i) {
        const int idx = t + i * 256, row = idx >> 5, c4 = (idx & 31) * 4;
        *(floatx4*)&sB[row * 132 + c4] = *(const floatx4*)(srcV + row * 128 + c4);
    }
    __syncthreads();
#pragma unroll
    for (int h = 0; h < 4; ++h) {
        const int g = t + h * 256, kq = g >> 7, d = g & 127;
        f16x8 p;
#pragma unroll
        for (int e = 0; e < 8; ++e) p[e] = (f16)sB[(kq * 8 + e) * 132 + d];
        *(f16x8*)(tile + 16384 + g * 8) = p;
    }
}

// ---- main: S^T trick (no P transpose), BN=64, lazy softmax, hidden DMA ----
__global__ __launch_bounds__(256, 2)
void fattn4(const float* __restrict__ Q, const f16* __restrict__ ws,
            const int* __restrict__ mask, float* __restrict__ Out)
{
    __shared__ __align__(16) f16 sT[TILE_ELEMS];   // Khi | Klo | Vt

    const int tid  = threadIdx.x;
    const int w    = tid >> 6;
    const int lane = tid & 63;
    const int m    = lane & 15;
    const int quad = lane >> 4;
    const int id   = blockIdx.x;
    const int bh   = (id & 7) * 4 + ((id >> 3) & 3);   // XCD swizzle
    const int qt   = id >> 5;                          // 128-row q-tile

    // Q B-fragments (col=m=qrow, k=quad*8+j), hi/lo f16 split of (20*log2e)*q
    f16x8 qhi[2][4], qlo[2][4];
#pragma unroll
    for (int rt = 0; rt < 2; ++rt) {
        const int qrow = qt * 128 + w * 32 + rt * 16 + m;
        const float* qp = Q + ((size_t)(bh * SQ_ + qrow)) * D_;
#pragma unroll
        for (int c = 0; c < 4; ++c) {
            floatx4 a = *(const floatx4*)(qp + c * 32 + quad * 8);
            floatx4 b = *(const floatx4*)(qp + c * 32 + quad * 8 + 4);
#pragma unroll
            for (int j = 0; j < 4; ++j) {
                float x = a[j] * SCALE_L2E;
                f16 h = (f16)x;
                qhi[rt][c][j] = h; qlo[rt][c][j] = (f16)(x - (float)h);
            }
#pragma unroll
            for (int j = 0; j < 4; ++j) {
                float x = b[j] * SCALE_L2E;
                f16 h = (f16)x;
                qhi[rt][c][4 + j] = h; qlo[rt][c][4 + j] = (f16)(x - (float)h);
            }
        }
    }

    f16x4 ones4;
#pragma unroll
    for (int j = 0; j < 4; ++j) ones4[j] = (f16)1.0f;

    floatx4 O[2][8], lac[2];
    float mf[2] = {-INFINITY, -INFINITY};
#pragma unroll
    for (int rt = 0; rt < 2; ++rt) {
        lac[rt] = (floatx4){0.f, 0.f, 0.f, 0.f};
#pragma unroll
        for (int t = 0; t < 8; ++t) O[rt][t] = (floatx4){0.f, 0.f, 0.f, 0.f};
    }

    const f16* wsB = ws + (size_t)bh * 32 * TILE_ELEMS;

    // prologue DMA: whole tile 0 (K: 8 chunks/wave, V: 4 chunks/wave)
#pragma unroll
    for (int j = 0; j < 8; ++j)
        async16(wsB + (w * 8 + j) * 512 + lane * 8, &sT[(w * 8 + j) * 512]);
#pragma unroll
    for (int j = 0; j < 4; ++j)
        async16(wsB + 16384 + (w * 4 + j) * 512 + lane * 8, &sT[16384 + (w * 4 + j) * 512]);
    __syncthreads();

    for (int kt = 0; kt < 32; ++kt) {
        // ---- S^T = K · Q^T  (A=K frags from LDS, B=Q regs), 3-term f16 split ----
        floatx4 S[2][4];
#pragma unroll
        for (int rt = 0; rt < 2; ++rt)
#pragma unroll
            for (int nt = 0; nt < 4; ++nt) S[rt][nt] = (floatx4){0.f, 0.f, 0.f, 0.f};
#pragma unroll
        for (int c = 0; c < 4; ++c) {
#pragma unroll
            for (int nt = 0; nt < 4; ++nt) {
                const int g = (c * 4 + quad) * 64 + nt * 16 + m;
                f16x8 kh = *(const f16x8*)&sT[g * 8];
                f16x8 kl = *(const f16x8*)&sT[8192 + g * 8];
#pragma unroll
                for (int rt = 0; rt < 2; ++rt) {
                    S[rt][nt] = __builtin_amdgcn_mfma_f32_16x16x32_f16(kh, qhi[rt][c], S[rt][nt], 0, 0, 0);
                    S[rt][nt] = __builtin_amdgcn_mfma_f32_16x16x32_f16(kl, qhi[rt][c], S[rt][nt], 0, 0, 0);
                    S[rt][nt] = __builtin_amdgcn_mfma_f32_16x16x32_f16(kh, qlo[rt][c], S[rt][nt], 0, 0, 0);
                }
            }
        }

        __syncthreads();                 // M: K reads done; V(kt) DMA drained
        if (kt + 1 < 32) {               // DMA K(kt+1) — overlaps softmax+PV
            const f16* nk = wsB + (size_t)(kt + 1) * TILE_ELEMS;
#pragma unroll
            for (int j = 0; j < 8; ++j)
                async16(nk + (w * 8 + j) * 512 + lane * 8, &sT[(w * 8 + j) * 512]);
        }

        // ---- lazy online softmax (per-lane qrow = m; keys across regs/nt/quads) ----
        float mx[2];
#pragma unroll
        for (int rt = 0; rt < 2; ++rt) {
            float v0 = fmaxf(fmaxf(S[rt][0][0], S[rt][0][1]), fmaxf(S[rt][0][2], S[rt][0][3]));
            float v1 = fmaxf(fmaxf(S[rt][1][0], S[rt][1][1]), fmaxf(S[rt][1][2], S[rt][1][3]));
            float v2 = fmaxf(fmaxf(S[rt][2][0], S[rt][2][1]), fmaxf(S[rt][2][2], S[rt][2][3]));
            float v3 = fmaxf(fmaxf(S[rt][3][0], S[rt][3][1]), fmaxf(S[rt][3][2], S[rt][3][3]));
            float v = fmaxf(fmaxf(v0, v1), fmaxf(v2, v3));
            v = fmaxf(v, __shfl_xor(v, 16));
            v = fmaxf(v, __shfl_xor(v, 32));
            mx[rt] = v;
        }
        const bool upd = (mx[0] > mf[0] + TAU) || (mx[1] > mf[1] + TAU);
        if (__ballot(upd)) {
#pragma unroll
            for (int rt = 0; rt < 2; ++rt) {
                const float mn = fmaxf(mf[rt], mx[rt]);
                const float al = exp2f(mf[rt] - mn);
                mf[rt] = mn;
                lac[rt][0] *= al;
#pragma unroll
                for (int t = 0; t < 8; ++t)
#pragma unroll
                    for (int r = 0; r < 4; ++r) O[rt][t][r] *= al;
            }
        }

        // ---- P = exp2(S - mf), straight into PV B-frag registers (f16) ----
        f16x4 P[2][4];
#pragma unroll
        for (int rt = 0; rt < 2; ++rt)
#pragma unroll
            for (int nt = 0; nt < 4; ++nt)
#pragma unroll
                for (int r = 0; r < 4; ++r)
                    P[rt][nt][r] = (f16)exp2f(S[rt][nt][r] - mf[rt]);

        // row-sums l += P·1 via ones-MFMA (C-layout col = qrow, rows dup)
#pragma unroll
        for (int rt = 0; rt < 2; ++rt)
#pragma unroll
            for (int nt = 0; nt < 4; ++nt)
                lac[rt] = __builtin_amdgcn_mfma_f32_16x16x16f16(ones4, P[rt][nt], lac[rt], 0, 0, 0);

        // ---- O^T += V^T · P^T  (A=V frags, B=P regs) ----
#pragma unroll
        for (int t = 0; t < 8; ++t) {
#pragma unroll
            for (int nt = 0; nt < 4; ++nt) {
                f16x4 vf = *(const f16x4*)&sT[16384 +
                    ((nt * 2 + (quad >> 1)) * 128 + t * 16 + m) * 8 + (quad & 1) * 4];
                O[0][t] = __builtin_amdgcn_mfma_f32_16x16x16f16(vf, P[0][nt], O[0][t], 0, 0, 0);
                O[1][t] = __builtin_amdgcn_mfma_f32_16x16x16f16(vf, P[1][nt], O[1][t], 0, 0, 0);
            }
        }

        __syncthreads();                 // E: V reads done; K(kt+1) DMA drained
        if (kt + 1 < 32) {               // DMA V(kt+1) — overlaps next QK
            const f16* nv = wsB + (size_t)(kt + 1) * TILE_ELEMS + 16384;
#pragma unroll
            for (int j = 0; j < 4; ++j)
                async16(nv + (w * 4 + j) * 512 + lane * 8, &sT[16384 + (w * 4 + j) * 512]);
        }
    }

    // ---- epilogue: O^T lane holds col=qrow=m, rows d = t*16+quad*4+r ----
#pragma unroll
    for (int rt = 0; rt < 2; ++rt) {
        const float inv = 1.0f / lac[rt][0];
        const int qrow = qt * 128 + w * 32 + rt * 16 + m;
        float* outp = Out + ((size_t)(bh * SQ_ + qrow)) * D_;
#pragma unroll
        for (int t = 0; t < 8; ++t) {
            const int d0 = t * 16 + quad * 4;
            floatx4 o;
#pragma unroll
            for (int r = 0; r < 4; ++r) {
                const float mk = (mask[d0 + r] != 0) ? 0.0f : 1.0f;
                o[r] = O[rt][t][r] * inv * mk;
            }
            *(floatx4*)(outp + d0) = o;
        }
    }
}

// ---------------- fallback (R2 kernel, known-passing) if ws too small ----------------
#define KSTR 136
#define VSTR 40
#define PSTR 40
__global__ __launch_bounds__(256, 2)
void fattn_kernel(const float* __restrict__ Q, const float* __restrict__ K,
                  const float* __restrict__ V, const int* __restrict__ mask,
                  float* __restrict__ Out)
{
    __shared__ __align__(16) __bf16 sKhi[32 * KSTR];
    __shared__ __align__(16) __bf16 sKlo[32 * KSTR];
    __shared__ __align__(16) __bf16 sVt[128 * VSTR];
    __shared__ __align__(16) __bf16 sP2[4 * 16 * PSTR];

    const int tid  = threadIdx.x;
    const int w    = tid >> 6;
    const int lane = tid & 63;
    const int m    = lane & 15;
    const int quad = lane >> 4;
    const int qt   = blockIdx.x;
    const int bh   = blockIdx.y;

    bf16x8 qhi[4], qlo[4];
    {
        const int qrow = qt * 64 + w * 16 + m;
        const float* qp = Q + ((size_t)(bh * SQ_ + qrow)) * D_;
#pragma unroll
        for (int c = 0; c < 4; ++c) {
            const int d0 = c * 32 + quad * 8;
            floatx4 a = *(const floatx4*)(qp + d0);
            floatx4 b = *(const floatx4*)(qp + d0 + 4);
#pragma unroll
            for (int j = 0; j < 4; ++j) {
                float x = a[j] * 20.0f;
                __bf16 h = (__bf16)x;
                qhi[c][j] = h; qlo[c][j] = (__bf16)(x - (float)h);
            }
#pragma unroll
            for (int j = 0; j < 4; ++j) {
                float x = b[j] * 20.0f;
                __bf16 h = (__bf16)x;
                qhi[c][4 + j] = h; qlo[c][4 + j] = (__bf16)(x - (float)h);
            }
        }
    }

    floatx4 O[8];
#pragma unroll
    for (int t = 0; t < 8; ++t) O[t] = (floatx4){0.f, 0.f, 0.f, 0.f};
    float m_i[4] = {-INFINITY, -INFINITY, -INFINITY, -INFINITY};
    float l_i[4] = {0.f, 0.f, 0.f, 0.f};

    const float* Kbh = K + (size_t)bh * SK_ * D_;
    const float* Vbh = V + (size_t)bh * SK_ * D_;
    __bf16* sPw = sP2 + w * 16 * PSTR;

    for (int kt = 0; kt < SK_ / 32; ++kt) {
        const int kbase = kt * 32;
#pragma unroll
        for (int i = 0; i < 4; ++i) {
            const int lin = i * 1024 + tid * 4;
            const int key = lin >> 7;
            const int d   = lin & 127;
            floatx4 v = *(const floatx4*)(Kbh + (kbase + key) * D_ + d);
            bf16x4 h4, l4;
#pragma unroll
            for (int j = 0; j < 4; ++j) {
                __bf16 h = (__bf16)v[j]; h4[j] = h; l4[j] = (__bf16)(v[j] - (float)h);
            }
            *(bf16x4*)&sKhi[key * KSTR + d] = h4;
            *(bf16x4*)&sKlo[key * KSTR + d] = l4;
        }
#pragma unroll
        for (int i = 0; i < 2; ++i) {
            const int pi   = i * 256 + tid;
            const int kp   = (pi & 15) * 2;
            const int dblk = (pi >> 4);
            const int d0   = dblk * 4;
            floatx4 v0 = *(const floatx4*)(Vbh + (kbase + kp) * D_ + d0);
            floatx4 v1 = *(const floatx4*)(Vbh + (kbase + kp + 1) * D_ + d0);
#pragma unroll
            for (int j = 0; j < 4; ++j) {
                bf16x2 p2; p2[0] = (__bf16)v0[j]; p2[1] = (__bf16)v1[j];
                *(bf16x2*)&sVt[(d0 + j) * VSTR + kp] = p2;
            }
        }
        __syncthreads();

        floatx4 Sv[2];
#pragma unroll
        for (int nt = 0; nt < 2; ++nt) {
            floatx4 acc = (floatx4){0.f, 0.f, 0.f, 0.f};
#pragma unroll
            for (int c = 0; c < 4; ++c) {
                const int off = (nt * 16 + m) * KSTR + c * 32 + quad * 8;
                bf16x8 kh = *(const bf16x8*)&sKhi[off];
                bf16x8 kl = *(const bf16x8*)&sKlo[off];
                acc = __builtin_amdgcn_mfma_f32_16x16x32_bf16(qhi[c], kh, acc, 0, 0, 0);
                acc = __builtin_amdgcn_mfma_f32_16x16x32_bf16(qlo[c], kh, acc, 0, 0, 0);
                acc = __builtin_amdgcn_mfma_f32_16x16x32_bf16(qhi[c], kl, acc, 0, 0, 0);
            }
            Sv[nt] = acc;
        }

        float alpha[4];
#pragma unroll
        for (int r = 0; r < 4; ++r) {
            float tmax = fmaxf(Sv[0][r], Sv[1][r]);
#pragma unroll
            for (int off = 1; off < 16; off <<= 1)
                tmax = fmaxf(tmax, __shfl_xor(tmax, off, 64));
            const float mn = fmaxf(m_i[r], tmax);
            const float a  = __expf(m_i[r] - mn);
            const float p0 = __expf(Sv[0][r] - mn);
            const float p1 = __expf(Sv[1][r] - mn);
            Sv[0][r] = p0; Sv[1][r] = p1;
            float rs = p0 + p1;
#pragma unroll
            for (int off = 1; off < 16; off <<= 1)
                rs += __shfl_xor(rs, off, 64);
            l_i[r] = l_i[r] * a + rs;
            m_i[r] = mn;
            alpha[r] = a;
        }
#pragma unroll
        for (int t = 0; t < 8; ++t)
#pragma unroll
            for (int r = 0; r < 4; ++r)
                O[t][r] *= alpha[r];

#pragma unroll
        for (int r = 0; r < 4; ++r) {
            sPw[(quad * 4 + r) * PSTR + m]      = (__bf16)Sv[0][r];
            sPw[(quad * 4 + r) * PSTR + 16 + m] = (__bf16)Sv[1][r];
        }
        __asm__ volatile("s_waitcnt lgkmcnt(0)" ::: "memory");
        bf16x8 pf = *(const bf16x8*)&sPw[m * PSTR + quad * 8];

#pragma unroll
        for (int t = 0; t < 8; ++t) {
            bf16x8 vf = *(const bf16x8*)&sVt[(t * 16 + m) * VSTR + quad * 8];
            O[t] = __builtin_amdgcn_mfma_f32_16x16x32_bf16(pf, vf, O[t], 0, 0, 0);
        }
        __syncthreads();
    }

    float inv[4];
#pragma unroll
    for (int r = 0; r < 4; ++r) inv[r] = 1.0f / l_i[r];
    const int qrow0 = qt * 64 + w * 16 + quad * 4;
    float* outp = Out + ((size_t)(bh * SQ_ + qrow0)) * D_;
#pragma unroll
    for (int t = 0; t < 8; ++t) {
        const int d = t * 16 + m;
        const float mk = (mask[d] != 0) ? 0.0f : 1.0f;
#pragma unroll
        for (int r = 0; r < 4; ++r)
            outp[r * D_ + d] = O[t][r] * inv[r] * mk;
    }
}

extern "C" void kernel_launch(void* const* d_in, const int* in_sizes, int n_in,
                              void* d_out, int out_size, void* d_ws, size_t ws_size,
                              hipStream_t stream) {
    const float* Q = (const float*)d_in[0];
    const float* K = (const float*)d_in[1];
    const float* V = (const float*)d_in[2];
    const int* mask = (const int*)d_in[3];
    float* out = (float*)d_out;

    if (ws_size >= WS_NEED) {
        f16* ws = (f16*)d_ws;
        prep<<<1024, 256, 0, stream>>>(K, V, ws);
        fattn4<<<512, 256, 0, stream>>>(Q, ws, mask, out);
    } else {
        dim3 grid(SQ_ / 64, BH_);
        fattn_kernel<<<grid, 256, 0, stream>>>(Q, K, V, mask, out);
    }
}